// Round 1
// baseline (32794.202 us; speedup 1.0000x reference)
//
#include <hip/hip_runtime.h>

// out[b,n,f] = sum_{l,m} x1[b,l,f] * x2[b,m,f] * cg[l,m,n]
// B=50000, d1=d2=9, d3=25, MUL=512, fp32.
// One block per b; 256 threads x float2 = 512 f-channels.
// CG block sparsity (|l1-l2| <= l3 <= l1+l2) hardcoded: 81 muls + 1225 FMAs
// per element instead of dense 2025. cg reads are wave-uniform const offsets
// -> scalar loads on the SMEM pipe, parallel to VALU.

#define BATCH 50000
#define D1 9
#define D2 9
#define D3 25
#define MUL 512

__global__ void __launch_bounds__(256) tp_kernel(
    const float* __restrict__ x1,
    const float* __restrict__ x2,
    const float* __restrict__ cg,
    float* __restrict__ out) {

    const int b = blockIdx.x;
    const int tid = threadIdx.x;  // each thread: 2 consecutive f

    const float2* x1v = reinterpret_cast<const float2*>(x1) + (size_t)b * (D1 * MUL / 2);
    const float2* x2v = reinterpret_cast<const float2*>(x2) + (size_t)b * (D2 * MUL / 2);
    float2*       ov  = reinterpret_cast<float2*>(out)      + (size_t)b * (D3 * MUL / 2);

    float2 a[D1], c[D2], acc[D3];

    #pragma unroll
    for (int l = 0; l < D1; ++l) a[l] = x1v[l * (MUL / 2) + tid];
    #pragma unroll
    for (int m = 0; m < D2; ++m) c[m] = x2v[m * (MUL / 2) + tid];
    #pragma unroll
    for (int n = 0; n < D3; ++n) { acc[n].x = 0.0f; acc[n].y = 0.0f; }

    #pragma unroll
    for (int l1 = 0; l1 <= 2; ++l1)
    #pragma unroll
    for (int l2 = 0; l2 <= 2; ++l2)
    #pragma unroll
    for (int i = 0; i < 2 * l1 + 1; ++i)
    #pragma unroll
    for (int j = 0; j < 2 * l2 + 1; ++j) {
        const int L = l1 * l1 + i;
        const int M = l2 * l2 + j;
        const float px = a[L].x * c[M].x;
        const float py = a[L].y * c[M].y;
        #pragma unroll
        for (int l3 = (l1 > l2 ? l1 - l2 : l2 - l1); l3 <= l1 + l2; ++l3)
        #pragma unroll
        for (int k = 0; k < 2 * l3 + 1; ++k) {
            const int N = l3 * l3 + k;
            const float w = cg[(L * D2 + M) * D3 + N];  // uniform -> s_load
            acc[N].x = fmaf(px, w, acc[N].x);
            acc[N].y = fmaf(py, w, acc[N].y);
        }
    }

    #pragma unroll
    for (int n = 0; n < D3; ++n) ov[n * (MUL / 2) + tid] = acc[n];
}

extern "C" void kernel_launch(void* const* d_in, const int* in_sizes, int n_in,
                              void* d_out, int out_size, void* d_ws, size_t ws_size,
                              hipStream_t stream) {
    const float* x1 = (const float*)d_in[0];
    const float* x2 = (const float*)d_in[1];
    const float* cg = (const float*)d_in[2];
    float* out = (float*)d_out;

    dim3 grid(BATCH);
    dim3 block(256);
    tp_kernel<<<grid, block, 0, stream>>>(x1, x2, cg, out);
}

// Round 2
// 1511.923 us; speedup vs baseline: 21.6904x; 21.6904x over previous
//
#include <hip/hip_runtime.h>

// out[b,n,f] = sum_{l,m} x1[b,l,f] * x2[b,m,f] * cg[l,m,n]
// B=50000, d1=d2=9, d3=25, MUL=512, fp32.
// One block per b; 256 threads x float2 = 512 f-channels.
//
// R1 lesson: all loops MUST have literal constant bounds so clang fully
// unrolls innermost-first and SROA keeps a[]/c[]/acc[] in VGPRs. The SO(3)
// selection rule |l1-l2| <= l3 <= l1+l2 is an if() on constants -> folded.
// Previous variable-bound version left non-constant indices -> arrays
// demoted to LDS/scratch -> 166 GB of spill traffic, 33 ms.

#define BATCH 50000
#define D1 9
#define D2 9
#define D3 25
#define MUL 512

__global__ void __launch_bounds__(256) tp_kernel(
    const float* __restrict__ x1,
    const float* __restrict__ x2,
    const float* __restrict__ cg,
    float* __restrict__ out) {

    const int b = blockIdx.x;
    const int tid = threadIdx.x;  // each thread: 2 consecutive f

    const float2* x1v = reinterpret_cast<const float2*>(x1) + (size_t)b * (D1 * MUL / 2);
    const float2* x2v = reinterpret_cast<const float2*>(x2) + (size_t)b * (D2 * MUL / 2);
    float2*       ov  = reinterpret_cast<float2*>(out)      + (size_t)b * (D3 * MUL / 2);

    float2 a[D1], c[D2], acc[D3];

    #pragma unroll
    for (int l = 0; l < D1; ++l) a[l] = x1v[l * (MUL / 2) + tid];
    #pragma unroll
    for (int m = 0; m < D2; ++m) c[m] = x2v[m * (MUL / 2) + tid];
    #pragma unroll
    for (int n = 0; n < D3; ++n) { acc[n].x = 0.0f; acc[n].y = 0.0f; }

    #pragma unroll
    for (int L = 0; L < D1; ++L) {
        #pragma unroll
        for (int M = 0; M < D2; ++M) {
            const float px = a[L].x * c[M].x;
            const float py = a[L].y * c[M].y;
            #pragma unroll
            for (int N = 0; N < D3; ++N) {
                // constant-foldable after full unroll:
                const int l1 = (L >= 4) ? 2 : (L >= 1) ? 1 : 0;
                const int l2 = (M >= 4) ? 2 : (M >= 1) ? 1 : 0;
                const int l3 = (N >= 16) ? 4 : (N >= 9) ? 3 : (N >= 4) ? 2 : (N >= 1) ? 1 : 0;
                const int lo = (l1 > l2) ? (l1 - l2) : (l2 - l1);
                if (l3 >= lo && l3 <= l1 + l2) {
                    const float w = cg[(L * D2 + M) * D3 + N];  // uniform -> s_load
                    acc[N].x = fmaf(px, w, acc[N].x);
                    acc[N].y = fmaf(py, w, acc[N].y);
                }
            }
        }
    }

    #pragma unroll
    for (int n = 0; n < D3; ++n) ov[n * (MUL / 2) + tid] = acc[n];
}

extern "C" void kernel_launch(void* const* d_in, const int* in_sizes, int n_in,
                              void* d_out, int out_size, void* d_ws, size_t ws_size,
                              hipStream_t stream) {
    const float* x1 = (const float*)d_in[0];
    const float* x2 = (const float*)d_in[1];
    const float* cg = (const float*)d_in[2];
    float* out = (float*)d_out;

    dim3 grid(BATCH);
    dim3 block(256);
    tp_kernel<<<grid, block, 0, stream>>>(x1, x2, cg, out);
}